// Round 9
// baseline (495.274 us; speedup 1.0000x reference)
//
#include <hip/hip_runtime.h>
#include <hip/hip_fp16.h>
#include <stdint.h>

#define N_NODES 100000
#define N_EDGES 640000
#define R_REL   64
#define D_DIM   128
#define L_LAYERS 2

#define CAP 32            // bucket capacity per node (P(deg>=32)~4e-13; verified no drops in R8)

#define LDA 136   // bf16 tile stride (128 + 8 pad)
#define LDT 264   // bf16 t-tile stride (256 + 8 pad)
#define LDFY 132  // f32 y-tile stride (128 + 4 pad)
#define MROWS 128 // mlp tile rows
#define GMLP ((N_NODES + MROWS - 1) / MROWS)   // 782

#define SCAT_BLKS  (N_EDGES / 256)   // 2500
#define PREPM_BLKS 128               // gamma/beta MLP blocks
#define CONV_BLKS  256               // weight f32->bf16 conversion
#define XW_BLKS    (N_NODES / 32)    // 3125
#define PXW_BLKS   (PREPM_BLKS + CONV_BLKS + XW_BLKS)   // 3509

typedef __attribute__((ext_vector_type(8))) short   short8;   // 8 bf16 MFMA frag
typedef __attribute__((ext_vector_type(4))) unsigned short ushort4v;
typedef __attribute__((ext_vector_type(4))) float   f32x4;

__device__ __forceinline__ unsigned short f32_to_bf16(float f) {
  union { float f; uint32_t u; } v; v.f = f;
  uint32_t u = v.u;
  u += 0x7fffu + ((u >> 16) & 1u);   // RNE (finite inputs only)
  return (unsigned short)(u >> 16);
}
__device__ __forceinline__ unsigned short f2h(float f) {
  __half h = __float2half(f);
  return __half_as_ushort(h);
}
__device__ __forceinline__ __half2 u2h(unsigned int u) {
  union { unsigned int u; __half2 h; } v; v.u = u; return v.h;
}
__device__ __forceinline__ short8 frag_from_f32(const float* p) {
  float4 a = *(const float4*)p;
  float4 b = *(const float4*)(p + 4);
  short8 r;
  r[0] = (short)f32_to_bf16(a.x); r[1] = (short)f32_to_bf16(a.y);
  r[2] = (short)f32_to_bf16(a.z); r[3] = (short)f32_to_bf16(a.w);
  r[4] = (short)f32_to_bf16(b.x); r[5] = (short)f32_to_bf16(b.y);
  r[6] = (short)f32_to_bf16(b.z); r[7] = (short)f32_to_bf16(b.w);
  return r;
}

// ---------------------------------------------------------------------------
// bucket scatter — STANDALONE dispatch (R8 lesson: do not co-schedule the
// random-atomic pass with streaming roles; the atomic round-trips and the
// streaming traffic contend in the LLC/fabric queues and both collapse).
// slot = atomicAdd(cnt[dst]); bucket[dst*32+slot] = src | (type<<17).
// ---------------------------------------------------------------------------
__global__ __launch_bounds__(256)
void scatter_bucket_kernel(const int* __restrict__ ei, const int* __restrict__ et,
                           int* __restrict__ cnt, unsigned int* __restrict__ bucket) {
  int idx = blockIdx.x * 256 + threadIdx.x;
  int dst = ei[N_EDGES + idx];
  int slot = atomicAdd(&cnt[dst], 1);
  if (slot < CAP)
    bucket[(size_t)dst * CAP + slot] =
        (unsigned int)ei[idx] | ((unsigned int)et[idx] << 17);
}

// ---------------------------------------------------------------------------
// prep matvec phase: out[row] = act(bias[row] + dot(w[row][0..K), vin[0..K)))
// One output row per wave iteration: 64 lanes read w[row][lane*4..] (coalesced
// 1KB line-contiguous load), 4 FMAs, 6-step butterfly reduce. Input slice va
// is row-invariant -> held in registers. (R6 fix: old per-thread-row version
// touched 64 distinct cache lines per instruction -> L1-transaction-bound,
// the 99us/19%-occupancy tail.)
// ---------------------------------------------------------------------------
__device__ __forceinline__ void prep_phase(const float* __restrict__ wmat,
                                           const float* __restrict__ bias,
                                           const float* vin, float* vout,
                                           int K, bool relu, int wave, int lane) {
  float4 va = {0.f, 0.f, 0.f, 0.f};
  if (lane * 4 < K) va = *(const float4*)&vin[lane * 4];
  #pragma unroll 4
  for (int rr = 0; rr < 64; ++rr) {
    const int row = wave * 64 + rr;
    float s = 0.f;
    if (lane * 4 < K) {
      float4 wv = *(const float4*)&wmat[(size_t)row * K + lane * 4];
      s = wv.x * va.x + wv.y * va.y + wv.z * va.z + wv.w * va.w;
    }
    #pragma unroll
    for (int off = 32; off; off >>= 1) s += __shfl_xor(s, off);
    if (lane == 0) {
      float v = s + bias[row];
      vout[row] = relu ? fmaxf(v, 0.f) : v;
    }
  }
}

// ---------------------------------------------------------------------------
// prep_xw kernel: 3 atomic-free roles, mutually independent.
//  [0, 128)        gamma/beta MLP -> packed f16 gbb (coalesced prep_phase)
//  [128, 384)      weight f32->bf16 conversion (Wwb/mw0b/mw1b for later mlp)
//  [384, 3509)     xw(L0) = f16(embed @ Ww^T + Wb) — reads f32 Ww directly
//                  (inline bf16 cvt) so no dependency on the convert role.
// gbb layout per type t: lane l holds 4 halfs at t*256+l*4 = {g2l,g2l+1,b2l,b2l+1}
// ---------------------------------------------------------------------------
__global__ __launch_bounds__(256)
void prep_xw_kernel(const float* __restrict__ rel_emb,
                    const float* __restrict__ rmw0, const float* __restrict__ rmb0,
                    const float* __restrict__ rmw1, const float* __restrict__ rmb1,
                    const float* __restrict__ rmw2, const float* __restrict__ rmb2,
                    const float* __restrict__ rmw3, const float* __restrict__ rmb3,
                    unsigned short* __restrict__ gbb,
                    const float* __restrict__ Ww, const float* __restrict__ mw0,
                    const float* __restrict__ mw1,
                    unsigned short* __restrict__ Wwb, unsigned short* __restrict__ mw0b,
                    unsigned short* __restrict__ mw1b,
                    const float* __restrict__ x, const float* __restrict__ Wb,
                    unsigned short* __restrict__ xwb) {
  __shared__ unsigned short a_lds[32 * LDA];   // xw role
  __shared__ float bufA[2 * D_DIM];            // prep role
  __shared__ float bufB[2 * D_DIM];

  const int b = blockIdx.x;
  const int tid = threadIdx.x;

  if (b < PREPM_BLKS) {                        // ---- gamma/beta MLP role
    const int l = b >> 6, r = b & 63;
    const int wave = tid >> 6, lane = tid & 63;
    if (tid < D_DIM) bufA[tid] = rel_emb[(l * R_REL + r) * D_DIM + tid];
    __syncthreads();
    prep_phase(rmw0 + (size_t)l * 2 * D_DIM * D_DIM, rmb0 + l * 2 * D_DIM,
               bufA, bufB, D_DIM, true, wave, lane);
    __syncthreads();
    prep_phase(rmw1 + (size_t)l * 2 * D_DIM * 2 * D_DIM, rmb1 + l * 2 * D_DIM,
               bufB, bufA, 2 * D_DIM, true, wave, lane);
    __syncthreads();
    prep_phase(rmw2 + (size_t)l * 2 * D_DIM * 2 * D_DIM, rmb2 + l * 2 * D_DIM,
               bufA, bufB, 2 * D_DIM, true, wave, lane);
    __syncthreads();
    prep_phase(rmw3 + (size_t)l * 2 * D_DIM * 2 * D_DIM, rmb3 + l * 2 * D_DIM,
               bufB, bufA, 2 * D_DIM, false, wave, lane);
    __syncthreads();
    // pack gamma/beta into gbb
    const int t = l * R_REL + r;
    const int j = tid;
    float s = bufA[j];
    int slot = (j < D_DIM) ? ((j >> 1) * 4 + (j & 1))
                           : (((j - D_DIM) >> 1) * 4 + 2 + ((j - D_DIM) & 1));
    gbb[t * 256 + slot] = f2h(s);
    return;
  }

  if (b < PREPM_BLKS + CONV_BLKS) {            // ---- weight convert role
    int i = (b - PREPM_BLKS) * 256 + tid;      // 0..65535
    if (i < L_LAYERS * D_DIM * D_DIM)     Wwb[i]  = f32_to_bf16(Ww[i]);
    if (i < L_LAYERS * 2 * D_DIM * D_DIM) mw0b[i] = f32_to_bf16(mw0[i]);
    if (i < L_LAYERS * 2 * D_DIM * D_DIM) mw1b[i] = f32_to_bf16(mw1[i]);
    return;
  }

  // ---- xw(L0) role: xwb = f16(x @ Ww^T + Wb), Ww read as f32 + inline cvt
  const int m0 = (b - PREPM_BLKS - CONV_BLKS) * 32;

  for (int i = tid; i < 1024; i += 256) {
    int row = i >> 5, ch = i & 31;
    float4 v = *(const float4*)&x[(m0 + row) * D_DIM + ch * 4];
    ushort4v s;
    s[0] = f32_to_bf16(v.x); s[1] = f32_to_bf16(v.y);
    s[2] = f32_to_bf16(v.z); s[3] = f32_to_bf16(v.w);
    *(ushort4v*)&a_lds[row * LDA + ch * 4] = s;
  }
  __syncthreads();

  const int wave = tid >> 6, lane = tid & 63;
  const int lrow = lane & 15, quad = lane >> 4;
  const int n0 = wave * 32;

  f32x4 acc[2][2] = {};
  for (int ks = 0; ks < 128; ks += 32) {
    short8 a0 = *(const short8*)&a_lds[lrow * LDA + ks + quad * 8];
    short8 a1 = *(const short8*)&a_lds[(16 + lrow) * LDA + ks + quad * 8];
    short8 b0 = frag_from_f32(&Ww[(size_t)(n0 + lrow) * D_DIM + ks + quad * 8]);
    short8 b1 = frag_from_f32(&Ww[(size_t)(n0 + 16 + lrow) * D_DIM + ks + quad * 8]);
    acc[0][0] = __builtin_amdgcn_mfma_f32_16x16x32_bf16(a0, b0, acc[0][0], 0, 0, 0);
    acc[0][1] = __builtin_amdgcn_mfma_f32_16x16x32_bf16(a0, b1, acc[0][1], 0, 0, 0);
    acc[1][0] = __builtin_amdgcn_mfma_f32_16x16x32_bf16(a1, b0, acc[1][0], 0, 0, 0);
    acc[1][1] = __builtin_amdgcn_mfma_f32_16x16x32_bf16(a1, b1, acc[1][1], 0, 0, 0);
  }

  for (int mt = 0; mt < 2; ++mt)
    for (int nt = 0; nt < 2; ++nt)
      for (int rr = 0; rr < 4; ++rr) {
        int row = mt * 16 + quad * 4 + rr;
        int col = n0 + nt * 16 + lrow;
        xwb[(size_t)(m0 + row) * D_DIM + col] = f2h(acc[mt][nt][rr] + Wb[col]);
      }
}

// ---------------------------------------------------------------------------
// agg: one WAVE per node. Lane l owns cols {2l, 2l+1}; wave walks the node's
// bucket (contiguous 128B row, scalar loads); m = gamma*xw[src]+beta via one
// __hfma2, f32 register accumulation. 4-edge unroll pipelines gather latency.
// ---------------------------------------------------------------------------
__global__ __launch_bounds__(256)
void agg_kernel(const unsigned int* __restrict__ bucket, const int* __restrict__ cnt,
                const float* __restrict__ x, const unsigned short* __restrict__ xwb,
                const unsigned short* __restrict__ gbt, const float* __restrict__ eps,
                unsigned short* __restrict__ o) {
  const int lane = threadIdx.x & 63;
  const int n = __builtin_amdgcn_readfirstlane(blockIdx.x * 4 + (threadIdx.x >> 6));
  int cn = cnt[n]; if (cn > CAP) cn = CAP;
  const unsigned int* bk = bucket + (size_t)n * CAP;

  float acc0 = 0.0f, acc1 = 0.0f;
  int e = 0;
  for (; e + 4 <= cn; e += 4) {
    unsigned int d0 = bk[e], d1 = bk[e + 1], d2 = bk[e + 2], d3 = bk[e + 3];
    __half2 x0 = *(const __half2*)&xwb[(size_t)(d0 & 0x1FFFF) * D_DIM + lane * 2];
    __half2 x1 = *(const __half2*)&xwb[(size_t)(d1 & 0x1FFFF) * D_DIM + lane * 2];
    __half2 x2 = *(const __half2*)&xwb[(size_t)(d2 & 0x1FFFF) * D_DIM + lane * 2];
    __half2 x3 = *(const __half2*)&xwb[(size_t)(d3 & 0x1FFFF) * D_DIM + lane * 2];
    uint2 g0 = *(const uint2*)&gbt[(d0 >> 17) * 256 + lane * 4];
    uint2 g1 = *(const uint2*)&gbt[(d1 >> 17) * 256 + lane * 4];
    uint2 g2 = *(const uint2*)&gbt[(d2 >> 17) * 256 + lane * 4];
    uint2 g3 = *(const uint2*)&gbt[(d3 >> 17) * 256 + lane * 4];
    __half2 m0 = __hfma2(u2h(g0.x), x0, u2h(g0.y));
    __half2 m1 = __hfma2(u2h(g1.x), x1, u2h(g1.y));
    __half2 m2 = __hfma2(u2h(g2.x), x2, u2h(g2.y));
    __half2 m3 = __hfma2(u2h(g3.x), x3, u2h(g3.y));
    float2 f0 = __half22float2(m0), f1 = __half22float2(m1);
    float2 f2 = __half22float2(m2), f3 = __half22float2(m3);
    acc0 += (f0.x + f1.x) + (f2.x + f3.x);
    acc1 += (f0.y + f1.y) + (f2.y + f3.y);
  }
  if (e + 2 <= cn) {
    unsigned int d0 = bk[e], d1 = bk[e + 1];
    __half2 x0 = *(const __half2*)&xwb[(size_t)(d0 & 0x1FFFF) * D_DIM + lane * 2];
    __half2 x1 = *(const __half2*)&xwb[(size_t)(d1 & 0x1FFFF) * D_DIM + lane * 2];
    uint2 g0 = *(const uint2*)&gbt[(d0 >> 17) * 256 + lane * 4];
    uint2 g1 = *(const uint2*)&gbt[(d1 >> 17) * 256 + lane * 4];
    __half2 m0 = __hfma2(u2h(g0.x), x0, u2h(g0.y));
    __half2 m1 = __hfma2(u2h(g1.x), x1, u2h(g1.y));
    float2 f0 = __half22float2(m0), f1 = __half22float2(m1);
    acc0 += f0.x + f1.x;
    acc1 += f0.y + f1.y;
    e += 2;
  }
  if (e < cn) {
    unsigned int d0 = bk[e];
    __half2 x0 = *(const __half2*)&xwb[(size_t)(d0 & 0x1FFFF) * D_DIM + lane * 2];
    uint2 g0 = *(const uint2*)&gbt[(d0 >> 17) * 256 + lane * 4];
    __half2 m0 = __hfma2(u2h(g0.x), x0, u2h(g0.y));
    float2 f0 = __half22float2(m0);
    acc0 += f0.x;
    acc1 += f0.y;
  }

  const float e1v = 1.0f + eps[0];
  float2 xr = *(const float2*)&x[(size_t)n * D_DIM + lane * 2];
  unsigned int w = (unsigned int)f32_to_bf16(e1v * xr.x + acc0)
                 | ((unsigned int)f32_to_bf16(e1v * xr.y + acc1) << 16);
  *(unsigned int*)&o[(size_t)n * D_DIM + lane * 2] = w;
}

// ---------------------------------------------------------------------------
// mlp: block = 128 nodes, 8 waves. All outputs staged through LDS and written
// as full cache lines (float4 / short8 rows) — no partial-line amplification.
// LDS overlay timeline in one 67584 B buffer:
//   o tile [128][136]bf16 -> t tile [128][264]bf16 -> y tile [128][132]f32
//   -> (D) xw tile [128][136]f16
// ---------------------------------------------------------------------------
__global__ __launch_bounds__(512, 4)
void mlp_kernel(const unsigned short* __restrict__ o,
                const unsigned short* __restrict__ w0b, const float* __restrict__ b0,
                const unsigned short* __restrict__ w1b, const float* __restrict__ b1,
                float* __restrict__ y,
                const unsigned short* __restrict__ WwNb,  // next-layer Ww bf16 (or null)
                const float* __restrict__ WbN,            // next-layer bias
                unsigned short* __restrict__ xwbN) {      // next-layer xw f16 out
  __shared__ unsigned short u_lds[MROWS * LDT];   // 67584 B
  unsigned short* a_lds = u_lds;          // [128][LDA] bf16 o tile
  unsigned short* t_lds = u_lds;          // [128][LDT] bf16 t tile
  float*          yf    = (float*)u_lds;  // [128][LDFY] f32 y tile
  unsigned short* xs    = u_lds;          // [128][LDA] f16 xw tile

  const int tid = threadIdx.x;     // 0..511
  const int m0 = blockIdx.x * MROWS;

  // ---- stage o tile (clamp tail rows)
  for (int i = tid; i < MROWS * 16; i += 512) {
    int row = i >> 4, seg = i & 15;
    int rg = m0 + row; if (rg >= N_NODES) rg = N_NODES - 1;
    *(short8*)&a_lds[row * LDA + seg * 8] =
        *(const short8*)&o[(size_t)rg * D_DIM + seg * 8];
  }
  __syncthreads();

  const int wave = tid >> 6, lane = tid & 63;
  const int lrow = lane & 15, quad = lane >> 4;

  // ---- B: t = relu(o @ w0^T + b0); wave covers t cols [wave*32, +32)
  {
    const int n0 = wave * 32;
    f32x4 acc[8][2] = {};
    #pragma unroll
    for (int ks = 0; ks < 128; ks += 32) {
      short8 bf0 = *(const short8*)&w0b[(n0 + lrow) * D_DIM + ks + quad * 8];
      short8 bf1 = *(const short8*)&w0b[(n0 + 16 + lrow) * D_DIM + ks + quad * 8];
      #pragma unroll
      for (int mt = 0; mt < 8; ++mt) {
        short8 a = *(const short8*)&a_lds[(mt * 16 + lrow) * LDA + ks + quad * 8];
        acc[mt][0] = __builtin_amdgcn_mfma_f32_16x16x32_bf16(a, bf0, acc[mt][0], 0, 0, 0);
        acc[mt][1] = __builtin_amdgcn_mfma_f32_16x16x32_bf16(a, bf1, acc[mt][1], 0, 0, 0);
      }
    }
    __syncthreads();   // a dead
    float bb0 = b0[n0 + lrow], bb1 = b0[n0 + 16 + lrow];
    #pragma unroll
    for (int mt = 0; mt < 8; ++mt)
      #pragma unroll
      for (int rr = 0; rr < 4; ++rr) {
        int row = mt * 16 + quad * 4 + rr;
        t_lds[row * LDT + n0 + lrow]      = f32_to_bf16(fmaxf(acc[mt][0][rr] + bb0, 0.0f));
        t_lds[row * LDT + n0 + 16 + lrow] = f32_to_bf16(fmaxf(acc[mt][1][rr] + bb1, 0.0f));
      }
  }
  __syncthreads();

  // ---- C: y = t @ w1^T + b1; wave covers y cols [wave*16, +16)
  {
    const int n0 = wave * 16;
    f32x4 acc[8] = {};
    #pragma unroll
    for (int ks = 0; ks < 256; ks += 32) {
      short8 bf = *(const short8*)&w1b[(n0 + lrow) * 2 * D_DIM + ks + quad * 8];
      #pragma unroll
      for (int mt = 0; mt < 8; ++mt) {
        short8 a = *(const short8*)&t_lds[(mt * 16 + lrow) * LDT + ks + quad * 8];
        acc[mt] = __builtin_amdgcn_mfma_f32_16x16x32_bf16(a, bf, acc[mt], 0, 0, 0);
      }
    }
    __syncthreads();   // t dead
    float bb = b1[n0 + lrow];
    #pragma unroll
    for (int mt = 0; mt < 8; ++mt)
      #pragma unroll
      for (int rr = 0; rr < 4; ++rr) {
        int row = mt * 16 + quad * 4 + rr;
        yf[row * LDFY + n0 + lrow] = acc[mt][rr] + bb;
      }
  }
  __syncthreads();   // y tile complete

  // ---- cooperative y write: full 512B rows, float4 per lane
  for (int i = tid; i < MROWS * 32; i += 512) {
    int row = i >> 5, c4 = i & 31;
    int rg = m0 + row;
    if (rg < N_NODES)
      *(float4*)&y[(size_t)rg * D_DIM + c4 * 4] = *(const float4*)&yf[row * LDFY + c4 * 4];
  }

  // ---- D (fused next-layer xw): xwbN = f16(y @ WwN^T + WbN)
  if (xwbN) {
    const int n0 = wave * 16;
    f32x4 acc[8] = {};
    #pragma unroll
    for (int ks = 0; ks < 128; ks += 32) {
      short8 bf = *(const short8*)&WwNb[(n0 + lrow) * D_DIM + ks + quad * 8];
      #pragma unroll
      for (int mt = 0; mt < 8; ++mt) {
        short8 a = frag_from_f32(&yf[(mt * 16 + lrow) * LDFY + ks + quad * 8]);
        acc[mt] = __builtin_amdgcn_mfma_f32_16x16x32_bf16(a, bf, acc[mt], 0, 0, 0);
      }
    }
    __syncthreads();   // yf dead (also guarantees y-write loop reads done)
    float bb = WbN[n0 + lrow];
    #pragma unroll
    for (int mt = 0; mt < 8; ++mt)
      #pragma unroll
      for (int rr = 0; rr < 4; ++rr) {
        int row = mt * 16 + quad * 4 + rr;
        xs[row * LDA + n0 + lrow] = f2h(acc[mt][rr] + bb);
      }
    __syncthreads();   // xw tile complete
    // cooperative xwb write: full 256B rows, short8 per lane
    for (int i = tid; i < MROWS * 16; i += 512) {
      int row = i >> 4, seg = i & 15;
      int rg = m0 + row;
      if (rg < N_NODES)
        *(short8*)&xwbN[(size_t)rg * D_DIM + seg * 8] = *(const short8*)&xs[row * LDA + seg * 8];
    }
  }
}

// ---------------------------------------------------------------------------
extern "C" void kernel_launch(void* const* d_in, const int* in_sizes, int n_in,
                              void* d_out, int out_size, void* d_ws, size_t ws_size,
                              hipStream_t stream) {
  const int*   ei      = (const int*)d_in[0];
  const int*   et      = (const int*)d_in[1];
  const float* embed   = (const float*)d_in[2];
  const float* rel_emb = (const float*)d_in[3];
  const float* rmw0 = (const float*)d_in[4];  const float* rmb0 = (const float*)d_in[5];
  const float* rmw1 = (const float*)d_in[6];  const float* rmb1 = (const float*)d_in[7];
  const float* rmw2 = (const float*)d_in[8];  const float* rmb2 = (const float*)d_in[9];
  const float* rmw3 = (const float*)d_in[10]; const float* rmb3 = (const float*)d_in[11];
  const float* Ww   = (const float*)d_in[12]; const float* Wb   = (const float*)d_in[13];
  const float* mw0  = (const float*)d_in[14]; const float* mb0  = (const float*)d_in[15];
  const float* mw1  = (const float*)d_in[16]; const float* mb1  = (const float*)d_in[17];
  const float* eps  = (const float*)d_in[18];
  float* out = (float*)d_out;

  // workspace layout
  float*          W1   = (float*)d_ws;                          // N*D f32
  unsigned short* xwb  = (unsigned short*)(W1 + (size_t)N_NODES * D_DIM);  // N*D f16
  unsigned short* gbb  = xwb + (size_t)N_NODES * D_DIM;         // L*R*256 f16
  unsigned short* Wwb  = gbb + L_LAYERS * R_REL * 256;          // L*128*128 bf16
  unsigned short* mw0b = Wwb + L_LAYERS * D_DIM * D_DIM;        // L*256*128 bf16
  unsigned short* mw1b = mw0b + L_LAYERS * 2 * D_DIM * D_DIM;   // L*128*256 bf16
  int*   cnt     = (int*)(mw1b + L_LAYERS * 2 * D_DIM * D_DIM); // N
  unsigned int* bucket = (unsigned int*)(cnt + N_NODES);        // N*CAP u32
  unsigned short* obuf = (unsigned short*)(bucket + (size_t)N_NODES * CAP); // N*D bf16

  // ---- preprocessing: atomic pass ALONE, then the atomic-free fused pass
  hipMemsetAsync(cnt, 0, N_NODES * sizeof(int), stream);
  scatter_bucket_kernel<<<SCAT_BLKS, 256, 0, stream>>>(ei, et, cnt, bucket);
  prep_xw_kernel<<<PXW_BLKS, 256, 0, stream>>>(
      rel_emb, rmw0, rmb0, rmw1, rmb1, rmw2, rmb2, rmw3, rmb3, gbb,
      Ww, mw0, mw1, Wwb, mw0b, mw1b,
      embed, Wb, xwb);

  const int gA = N_NODES / 4;         // 25000 (wave per node)

  // ---- layer 0 (mlp fuses next-layer xw as phase D)
  agg_kernel<<<gA, 256, 0, stream>>>(bucket, cnt, embed, xwb, gbb, eps, obuf);
  mlp_kernel<<<GMLP, 512, 0, stream>>>(obuf, mw0b, mb0, mw1b, mb1, W1,
                                       Wwb + D_DIM * D_DIM, Wb + D_DIM, xwb);

  // ---- layer 1
  agg_kernel<<<gA, 256, 0, stream>>>(bucket, cnt, W1, xwb,
                                     gbb + R_REL * 256, eps + 1, obuf);
  mlp_kernel<<<GMLP, 512, 0, stream>>>(obuf, mw0b + 2 * D_DIM * D_DIM, mb0 + 2 * D_DIM,
                                       mw1b + 2 * D_DIM * D_DIM, mb1 + D_DIM, out,
                                       nullptr, nullptr, nullptr);
}

// Round 10
// 411.896 us; speedup vs baseline: 1.2024x; 1.2024x over previous
//
#include <hip/hip_runtime.h>
#include <hip/hip_fp16.h>
#include <stdint.h>

#define N_NODES 100000
#define N_EDGES 640000
#define R_REL   64
#define D_DIM   128
#define L_LAYERS 2

#define CAP 32            // bucket capacity per node (P(deg>=32)~4e-13; verified no drops R8/R9)

#define LDA 136   // bf16 tile stride (128 + 8 pad)
#define LDT 264   // bf16 t-tile stride (256 + 8 pad)
#define LDFY 132  // f32 y-tile stride (128 + 4 pad)
#define LDP 264   // f16 prep activation stride (256 + 8 pad)
#define MROWS 128 // mlp tile rows
#define GMLP ((N_NODES + MROWS - 1) / MROWS)   // 782

#define SCAT_BLKS  (N_EDGES / 256)   // 2500
#define CONV_BLKS  256               // weight f32->bf16 conversion
#define XW_BLKS    (N_NODES / 32)    // 3125

typedef __attribute__((ext_vector_type(8))) short    short8;   // 8 bf16 MFMA frag
typedef __attribute__((ext_vector_type(8))) _Float16 half8;    // 8 f16 MFMA frag
typedef __attribute__((ext_vector_type(4))) unsigned short ushort4v;
typedef __attribute__((ext_vector_type(4))) float    f32x4;

__device__ __forceinline__ unsigned short f32_to_bf16(float f) {
  union { float f; uint32_t u; } v; v.f = f;
  uint32_t u = v.u;
  u += 0x7fffu + ((u >> 16) & 1u);   // RNE (finite inputs only)
  return (unsigned short)(u >> 16);
}
__device__ __forceinline__ unsigned short f2h(float f) {
  __half h = __float2half(f);
  return __half_as_ushort(h);
}
__device__ __forceinline__ __half2 u2h(unsigned int u) {
  union { unsigned int u; __half2 h; } v; v.u = u; return v.h;
}
__device__ __forceinline__ short8 frag_from_f32(const float* p) {
  float4 a = *(const float4*)p;
  float4 b = *(const float4*)(p + 4);
  short8 r;
  r[0] = (short)f32_to_bf16(a.x); r[1] = (short)f32_to_bf16(a.y);
  r[2] = (short)f32_to_bf16(a.z); r[3] = (short)f32_to_bf16(a.w);
  r[4] = (short)f32_to_bf16(b.x); r[5] = (short)f32_to_bf16(b.y);
  r[6] = (short)f32_to_bf16(b.z); r[7] = (short)f32_to_bf16(b.w);
  return r;
}
__device__ __forceinline__ half8 hfrag_from_f32(const float* p) {
  float4 a = *(const float4*)p;
  float4 b = *(const float4*)(p + 4);
  half8 r;
  r[0] = (_Float16)a.x; r[1] = (_Float16)a.y;
  r[2] = (_Float16)a.z; r[3] = (_Float16)a.w;
  r[4] = (_Float16)b.x; r[5] = (_Float16)b.y;
  r[6] = (_Float16)b.z; r[7] = (_Float16)b.w;
  return r;
}

// ---------------------------------------------------------------------------
// bucket scatter — standalone dispatch (R8 lesson: random-atomic pass must not
// be co-scheduled with streaming roles). slot = atomicAdd(cnt[dst]);
// bucket[dst*32+slot] = src | (type<<17).
// ---------------------------------------------------------------------------
__global__ __launch_bounds__(256)
void scatter_bucket_kernel(const int* __restrict__ ei, const int* __restrict__ et,
                           int* __restrict__ cnt, unsigned int* __restrict__ bucket) {
  int idx = blockIdx.x * 256 + threadIdx.x;
  int dst = ei[N_EDGES + idx];
  int slot = atomicAdd(&cnt[dst], 1);
  if (slot < CAP)
    bucket[(size_t)dst * CAP + slot] =
        (unsigned int)ei[idx] | ((unsigned int)et[idx] << 17);
}

// ---------------------------------------------------------------------------
// prep as MFMA GEMM chain (R9 lesson: hand-rolled matvec reductions are
// latency-bound with no TLP — 99-198us tails. The chain is a 64x256 GEMM x4).
// One block per l (2 blocks, 256 thr = 4 waves x 64 cols). f16 MFMA, f32 acc;
// LDS ping-pong [64][LDP] f16 x2. Final phase writes packed gbb directly.
// ---------------------------------------------------------------------------
template<int K, bool RELU, bool FINAL>
__device__ __forceinline__ void prep_gemm(const unsigned short* __restrict__ inb,
                                          const float* __restrict__ W,
                                          const float* __restrict__ bias,
                                          unsigned short* __restrict__ outb,
                                          unsigned short* __restrict__ gbb_l,
                                          int wave, int lrow, int quad) {
  const int n0 = wave * 64;
  f32x4 acc[4][4] = {};
  for (int ks = 0; ks < K; ks += 32) {
    half8 bf[4];
    #pragma unroll
    for (int nt = 0; nt < 4; ++nt)
      bf[nt] = hfrag_from_f32(&W[(size_t)(n0 + nt * 16 + lrow) * K + ks + quad * 8]);
    #pragma unroll
    for (int mt = 0; mt < 4; ++mt) {
      half8 a = *(const half8*)&inb[(mt * 16 + lrow) * LDP + ks + quad * 8];
      #pragma unroll
      for (int nt = 0; nt < 4; ++nt)
        acc[mt][nt] = __builtin_amdgcn_mfma_f32_16x16x32_f16(a, bf[nt], acc[mt][nt], 0, 0, 0);
    }
  }
  #pragma unroll
  for (int mt = 0; mt < 4; ++mt)
    #pragma unroll
    for (int nt = 0; nt < 4; ++nt) {
      int col = n0 + nt * 16 + lrow;
      float bb = bias[col];
      #pragma unroll
      for (int rr = 0; rr < 4; ++rr) {
        int row = mt * 16 + quad * 4 + rr;
        float v = acc[mt][nt][rr] + bb;
        if (RELU) v = fmaxf(v, 0.f);
        if (!FINAL) {
          outb[row * LDP + col] = f2h(v);
        } else {
          int slot = (col < D_DIM) ? ((col >> 1) * 4 + (col & 1))
                                   : (((col - D_DIM) >> 1) * 4 + 2 + ((col - D_DIM) & 1));
          gbb_l[row * 256 + slot] = f2h(v);
        }
      }
    }
}

__global__ __launch_bounds__(256)
void prep_mfma_kernel(const float* __restrict__ rel_emb,
                      const float* __restrict__ rmw0, const float* __restrict__ rmb0,
                      const float* __restrict__ rmw1, const float* __restrict__ rmb1,
                      const float* __restrict__ rmw2, const float* __restrict__ rmb2,
                      const float* __restrict__ rmw3, const float* __restrict__ rmb3,
                      unsigned short* __restrict__ gbb) {
  __shared__ unsigned short bufX[64 * LDP];   // 33792 B (f16 bits)
  __shared__ unsigned short bufY[64 * LDP];   // 33792 B
  const int l = blockIdx.x;                   // 0..1
  const int tid = threadIdx.x;
  const int wave = tid >> 6, lane = tid & 63;
  const int lrow = lane & 15, quad = lane >> 4;

  // stage rel_emb[l] (64 x 128 f32) -> f16 bufX
  for (int i = tid; i < 64 * 32; i += 256) {
    int row = i >> 5, c4 = i & 31;
    float4 v = *(const float4*)&rel_emb[(size_t)(l * R_REL + row) * D_DIM + c4 * 4];
    ushort4v s;
    s[0] = f2h(v.x); s[1] = f2h(v.y); s[2] = f2h(v.z); s[3] = f2h(v.w);
    *(ushort4v*)&bufX[row * LDP + c4 * 4] = s;
  }
  __syncthreads();

  prep_gemm<128, true, false>(bufX, rmw0 + (size_t)l * 256 * 128, rmb0 + l * 256,
                              bufY, nullptr, wave, lrow, quad);
  __syncthreads();
  prep_gemm<256, true, false>(bufY, rmw1 + (size_t)l * 256 * 256, rmb1 + l * 256,
                              bufX, nullptr, wave, lrow, quad);
  __syncthreads();
  prep_gemm<256, true, false>(bufX, rmw2 + (size_t)l * 256 * 256, rmb2 + l * 256,
                              bufY, nullptr, wave, lrow, quad);
  __syncthreads();
  prep_gemm<256, false, true>(bufY, rmw3 + (size_t)l * 256 * 256, rmb3 + l * 256,
                              nullptr, gbb + (size_t)l * R_REL * 256, wave, lrow, quad);
}

// ---------------------------------------------------------------------------
// conv_xw: atomic-free fused pass.
//  [0, 256)       weight f32->bf16 conversion (Wwb/mw0b/mw1b for later mlp)
//  [256, 3381)    xw(L0) = f16(embed @ Ww^T + Wb) — reads f32 Ww directly.
// ---------------------------------------------------------------------------
__global__ __launch_bounds__(256)
void conv_xw_kernel(const float* __restrict__ Ww, const float* __restrict__ mw0,
                    const float* __restrict__ mw1,
                    unsigned short* __restrict__ Wwb, unsigned short* __restrict__ mw0b,
                    unsigned short* __restrict__ mw1b,
                    const float* __restrict__ x, const float* __restrict__ Wb,
                    unsigned short* __restrict__ xwb) {
  __shared__ unsigned short a_lds[32 * LDA];
  const int b = blockIdx.x;
  const int tid = threadIdx.x;

  if (b < CONV_BLKS) {                         // ---- weight convert role
    int i = b * 256 + tid;                     // 0..65535
    if (i < L_LAYERS * D_DIM * D_DIM)     Wwb[i]  = f32_to_bf16(Ww[i]);
    if (i < L_LAYERS * 2 * D_DIM * D_DIM) mw0b[i] = f32_to_bf16(mw0[i]);
    if (i < L_LAYERS * 2 * D_DIM * D_DIM) mw1b[i] = f32_to_bf16(mw1[i]);
    return;
  }

  // ---- xw(L0) role
  const int m0 = (b - CONV_BLKS) * 32;

  for (int i = tid; i < 1024; i += 256) {
    int row = i >> 5, ch = i & 31;
    float4 v = *(const float4*)&x[(m0 + row) * D_DIM + ch * 4];
    ushort4v s;
    s[0] = f32_to_bf16(v.x); s[1] = f32_to_bf16(v.y);
    s[2] = f32_to_bf16(v.z); s[3] = f32_to_bf16(v.w);
    *(ushort4v*)&a_lds[row * LDA + ch * 4] = s;
  }
  __syncthreads();

  const int wave = tid >> 6, lane = tid & 63;
  const int lrow = lane & 15, quad = lane >> 4;
  const int n0 = wave * 32;

  f32x4 acc[2][2] = {};
  for (int ks = 0; ks < 128; ks += 32) {
    short8 a0 = *(const short8*)&a_lds[lrow * LDA + ks + quad * 8];
    short8 a1 = *(const short8*)&a_lds[(16 + lrow) * LDA + ks + quad * 8];
    short8 b0 = frag_from_f32(&Ww[(size_t)(n0 + lrow) * D_DIM + ks + quad * 8]);
    short8 b1 = frag_from_f32(&Ww[(size_t)(n0 + 16 + lrow) * D_DIM + ks + quad * 8]);
    acc[0][0] = __builtin_amdgcn_mfma_f32_16x16x32_bf16(a0, b0, acc[0][0], 0, 0, 0);
    acc[0][1] = __builtin_amdgcn_mfma_f32_16x16x32_bf16(a0, b1, acc[0][1], 0, 0, 0);
    acc[1][0] = __builtin_amdgcn_mfma_f32_16x16x32_bf16(a1, b0, acc[1][0], 0, 0, 0);
    acc[1][1] = __builtin_amdgcn_mfma_f32_16x16x32_bf16(a1, b1, acc[1][1], 0, 0, 0);
  }

  for (int mt = 0; mt < 2; ++mt)
    for (int nt = 0; nt < 2; ++nt)
      for (int rr = 0; rr < 4; ++rr) {
        int row = mt * 16 + quad * 4 + rr;
        int col = n0 + nt * 16 + lrow;
        xwb[(size_t)(m0 + row) * D_DIM + col] = f2h(acc[mt][nt][rr] + Wb[col]);
      }
}

// ---------------------------------------------------------------------------
// agg: one WAVE per node. Lane l owns cols {2l, 2l+1}; wave walks the node's
// bucket (contiguous 128B row, scalar loads); m = gamma*xw[src]+beta via one
// __hfma2, f32 register accumulation. 4-edge unroll pipelines gather latency.
// ---------------------------------------------------------------------------
__global__ __launch_bounds__(256)
void agg_kernel(const unsigned int* __restrict__ bucket, const int* __restrict__ cnt,
                const float* __restrict__ x, const unsigned short* __restrict__ xwb,
                const unsigned short* __restrict__ gbt, const float* __restrict__ eps,
                unsigned short* __restrict__ o) {
  const int lane = threadIdx.x & 63;
  const int n = __builtin_amdgcn_readfirstlane(blockIdx.x * 4 + (threadIdx.x >> 6));
  int cn = cnt[n]; if (cn > CAP) cn = CAP;
  const unsigned int* bk = bucket + (size_t)n * CAP;

  float acc0 = 0.0f, acc1 = 0.0f;
  int e = 0;
  for (; e + 4 <= cn; e += 4) {
    unsigned int d0 = bk[e], d1 = bk[e + 1], d2 = bk[e + 2], d3 = bk[e + 3];
    __half2 x0 = *(const __half2*)&xwb[(size_t)(d0 & 0x1FFFF) * D_DIM + lane * 2];
    __half2 x1 = *(const __half2*)&xwb[(size_t)(d1 & 0x1FFFF) * D_DIM + lane * 2];
    __half2 x2 = *(const __half2*)&xwb[(size_t)(d2 & 0x1FFFF) * D_DIM + lane * 2];
    __half2 x3 = *(const __half2*)&xwb[(size_t)(d3 & 0x1FFFF) * D_DIM + lane * 2];
    uint2 g0 = *(const uint2*)&gbt[(d0 >> 17) * 256 + lane * 4];
    uint2 g1 = *(const uint2*)&gbt[(d1 >> 17) * 256 + lane * 4];
    uint2 g2 = *(const uint2*)&gbt[(d2 >> 17) * 256 + lane * 4];
    uint2 g3 = *(const uint2*)&gbt[(d3 >> 17) * 256 + lane * 4];
    __half2 m0 = __hfma2(u2h(g0.x), x0, u2h(g0.y));
    __half2 m1 = __hfma2(u2h(g1.x), x1, u2h(g1.y));
    __half2 m2 = __hfma2(u2h(g2.x), x2, u2h(g2.y));
    __half2 m3 = __hfma2(u2h(g3.x), x3, u2h(g3.y));
    float2 f0 = __half22float2(m0), f1 = __half22float2(m1);
    float2 f2 = __half22float2(m2), f3 = __half22float2(m3);
    acc0 += (f0.x + f1.x) + (f2.x + f3.x);
    acc1 += (f0.y + f1.y) + (f2.y + f3.y);
  }
  if (e + 2 <= cn) {
    unsigned int d0 = bk[e], d1 = bk[e + 1];
    __half2 x0 = *(const __half2*)&xwb[(size_t)(d0 & 0x1FFFF) * D_DIM + lane * 2];
    __half2 x1 = *(const __half2*)&xwb[(size_t)(d1 & 0x1FFFF) * D_DIM + lane * 2];
    uint2 g0 = *(const uint2*)&gbt[(d0 >> 17) * 256 + lane * 4];
    uint2 g1 = *(const uint2*)&gbt[(d1 >> 17) * 256 + lane * 4];
    __half2 m0 = __hfma2(u2h(g0.x), x0, u2h(g0.y));
    __half2 m1 = __hfma2(u2h(g1.x), x1, u2h(g1.y));
    float2 f0 = __half22float2(m0), f1 = __half22float2(m1);
    acc0 += f0.x + f1.x;
    acc1 += f0.y + f1.y;
    e += 2;
  }
  if (e < cn) {
    unsigned int d0 = bk[e];
    __half2 x0 = *(const __half2*)&xwb[(size_t)(d0 & 0x1FFFF) * D_DIM + lane * 2];
    uint2 g0 = *(const uint2*)&gbt[(d0 >> 17) * 256 + lane * 4];
    __half2 m0 = __hfma2(u2h(g0.x), x0, u2h(g0.y));
    float2 f0 = __half22float2(m0);
    acc0 += f0.x;
    acc1 += f0.y;
  }

  const float e1v = 1.0f + eps[0];
  float2 xr = *(const float2*)&x[(size_t)n * D_DIM + lane * 2];
  unsigned int w = (unsigned int)f32_to_bf16(e1v * xr.x + acc0)
                 | ((unsigned int)f32_to_bf16(e1v * xr.y + acc1) << 16);
  *(unsigned int*)&o[(size_t)n * D_DIM + lane * 2] = w;
}

// ---------------------------------------------------------------------------
// mlp: block = 128 nodes, 8 waves. All outputs staged through LDS and written
// as full cache lines (float4 / short8 rows) — no partial-line amplification.
// LDS overlay timeline in one 67584 B buffer:
//   o tile [128][136]bf16 -> t tile [128][264]bf16 -> y tile [128][132]f32
//   -> (D) xw tile [128][136]f16
// ---------------------------------------------------------------------------
__global__ __launch_bounds__(512, 4)
void mlp_kernel(const unsigned short* __restrict__ o,
                const unsigned short* __restrict__ w0b, const float* __restrict__ b0,
                const unsigned short* __restrict__ w1b, const float* __restrict__ b1,
                float* __restrict__ y,
                const unsigned short* __restrict__ WwNb,  // next-layer Ww bf16 (or null)
                const float* __restrict__ WbN,            // next-layer bias
                unsigned short* __restrict__ xwbN) {      // next-layer xw f16 out
  __shared__ unsigned short u_lds[MROWS * LDT];   // 67584 B
  unsigned short* a_lds = u_lds;          // [128][LDA] bf16 o tile
  unsigned short* t_lds = u_lds;          // [128][LDT] bf16 t tile
  float*          yf    = (float*)u_lds;  // [128][LDFY] f32 y tile
  unsigned short* xs    = u_lds;          // [128][LDA] f16 xw tile

  const int tid = threadIdx.x;     // 0..511
  const int m0 = blockIdx.x * MROWS;

  // ---- stage o tile (clamp tail rows)
  for (int i = tid; i < MROWS * 16; i += 512) {
    int row = i >> 4, seg = i & 15;
    int rg = m0 + row; if (rg >= N_NODES) rg = N_NODES - 1;
    *(short8*)&a_lds[row * LDA + seg * 8] =
        *(const short8*)&o[(size_t)rg * D_DIM + seg * 8];
  }
  __syncthreads();

  const int wave = tid >> 6, lane = tid & 63;
  const int lrow = lane & 15, quad = lane >> 4;

  // ---- B: t = relu(o @ w0^T + b0); wave covers t cols [wave*32, +32)
  {
    const int n0 = wave * 32;
    f32x4 acc[8][2] = {};
    #pragma unroll
    for (int ks = 0; ks < 128; ks += 32) {
      short8 bf0 = *(const short8*)&w0b[(n0 + lrow) * D_DIM + ks + quad * 8];
      short8 bf1 = *(const short8*)&w0b[(n0 + 16 + lrow) * D_DIM + ks + quad * 8];
      #pragma unroll
      for (int mt = 0; mt < 8; ++mt) {
        short8 a = *(const short8*)&a_lds[(mt * 16 + lrow) * LDA + ks + quad * 8];
        acc[mt][0] = __builtin_amdgcn_mfma_f32_16x16x32_bf16(a, bf0, acc[mt][0], 0, 0, 0);
        acc[mt][1] = __builtin_amdgcn_mfma_f32_16x16x32_bf16(a, bf1, acc[mt][1], 0, 0, 0);
      }
    }
    __syncthreads();   // a dead
    float bb0 = b0[n0 + lrow], bb1 = b0[n0 + 16 + lrow];
    #pragma unroll
    for (int mt = 0; mt < 8; ++mt)
      #pragma unroll
      for (int rr = 0; rr < 4; ++rr) {
        int row = mt * 16 + quad * 4 + rr;
        t_lds[row * LDT + n0 + lrow]      = f32_to_bf16(fmaxf(acc[mt][0][rr] + bb0, 0.0f));
        t_lds[row * LDT + n0 + 16 + lrow] = f32_to_bf16(fmaxf(acc[mt][1][rr] + bb1, 0.0f));
      }
  }
  __syncthreads();

  // ---- C: y = t @ w1^T + b1; wave covers y cols [wave*16, +16)
  {
    const int n0 = wave * 16;
    f32x4 acc[8] = {};
    #pragma unroll
    for (int ks = 0; ks < 256; ks += 32) {
      short8 bf = *(const short8*)&w1b[(n0 + lrow) * 2 * D_DIM + ks + quad * 8];
      #pragma unroll
      for (int mt = 0; mt < 8; ++mt) {
        short8 a = *(const short8*)&t_lds[(mt * 16 + lrow) * LDT + ks + quad * 8];
        acc[mt] = __builtin_amdgcn_mfma_f32_16x16x32_bf16(a, bf, acc[mt], 0, 0, 0);
      }
    }
    __syncthreads();   // t dead
    float bb = b1[n0 + lrow];
    #pragma unroll
    for (int mt = 0; mt < 8; ++mt)
      #pragma unroll
      for (int rr = 0; rr < 4; ++rr) {
        int row = mt * 16 + quad * 4 + rr;
        yf[row * LDFY + n0 + lrow] = acc[mt][rr] + bb;
      }
  }
  __syncthreads();   // y tile complete

  // ---- cooperative y write: full 512B rows, float4 per lane
  for (int i = tid; i < MROWS * 32; i += 512) {
    int row = i >> 5, c4 = i & 31;
    int rg = m0 + row;
    if (rg < N_NODES)
      *(float4*)&y[(size_t)rg * D_DIM + c4 * 4] = *(const float4*)&yf[row * LDFY + c4 * 4];
  }

  // ---- D (fused next-layer xw): xwbN = f16(y @ WwN^T + WbN)
  if (xwbN) {
    const int n0 = wave * 16;
    f32x4 acc[8] = {};
    #pragma unroll
    for (int ks = 0; ks < 128; ks += 32) {
      short8 bf = *(const short8*)&WwNb[(n0 + lrow) * D_DIM + ks + quad * 8];
      #pragma unroll
      for (int mt = 0; mt < 8; ++mt) {
        short8 a = frag_from_f32(&yf[(mt * 16 + lrow) * LDFY + ks + quad * 8]);
        acc[mt] = __builtin_amdgcn_mfma_f32_16x16x32_bf16(a, bf, acc[mt], 0, 0, 0);
      }
    }
    __syncthreads();   // yf dead (also guarantees y-write loop reads done)
    float bb = WbN[n0 + lrow];
    #pragma unroll
    for (int mt = 0; mt < 8; ++mt)
      #pragma unroll
      for (int rr = 0; rr < 4; ++rr) {
        int row = mt * 16 + quad * 4 + rr;
        xs[row * LDA + n0 + lrow] = f2h(acc[mt][rr] + bb);
      }
    __syncthreads();   // xw tile complete
    // cooperative xwb write: full 256B rows, short8 per lane
    for (int i = tid; i < MROWS * 16; i += 512) {
      int row = i >> 4, seg = i & 15;
      int rg = m0 + row;
      if (rg < N_NODES)
        *(short8*)&xwbN[(size_t)rg * D_DIM + seg * 8] = *(const short8*)&xs[row * LDA + seg * 8];
    }
  }
}

// ---------------------------------------------------------------------------
extern "C" void kernel_launch(void* const* d_in, const int* in_sizes, int n_in,
                              void* d_out, int out_size, void* d_ws, size_t ws_size,
                              hipStream_t stream) {
  const int*   ei      = (const int*)d_in[0];
  const int*   et      = (const int*)d_in[1];
  const float* embed   = (const float*)d_in[2];
  const float* rel_emb = (const float*)d_in[3];
  const float* rmw0 = (const float*)d_in[4];  const float* rmb0 = (const float*)d_in[5];
  const float* rmw1 = (const float*)d_in[6];  const float* rmb1 = (const float*)d_in[7];
  const float* rmw2 = (const float*)d_in[8];  const float* rmb2 = (const float*)d_in[9];
  const float* rmw3 = (const float*)d_in[10]; const float* rmb3 = (const float*)d_in[11];
  const float* Ww   = (const float*)d_in[12]; const float* Wb   = (const float*)d_in[13];
  const float* mw0  = (const float*)d_in[14]; const float* mb0  = (const float*)d_in[15];
  const float* mw1  = (const float*)d_in[16]; const float* mb1  = (const float*)d_in[17];
  const float* eps  = (const float*)d_in[18];
  float* out = (float*)d_out;

  // workspace layout
  float*          W1   = (float*)d_ws;                          // N*D f32
  unsigned short* xwb  = (unsigned short*)(W1 + (size_t)N_NODES * D_DIM);  // N*D f16
  unsigned short* gbb  = xwb + (size_t)N_NODES * D_DIM;         // L*R*256 f16
  unsigned short* Wwb  = gbb + L_LAYERS * R_REL * 256;          // L*128*128 bf16
  unsigned short* mw0b = Wwb + L_LAYERS * D_DIM * D_DIM;        // L*256*128 bf16
  unsigned short* mw1b = mw0b + L_LAYERS * 2 * D_DIM * D_DIM;   // L*128*256 bf16
  int*   cnt     = (int*)(mw1b + L_LAYERS * 2 * D_DIM * D_DIM); // N
  unsigned int* bucket = (unsigned int*)(cnt + N_NODES);        // N*CAP u32
  unsigned short* obuf = (unsigned short*)(bucket + (size_t)N_NODES * CAP); // N*D bf16

  // ---- preprocessing: atomic pass alone; tiny MFMA prep; atomic-free fused pass
  hipMemsetAsync(cnt, 0, N_NODES * sizeof(int), stream);
  scatter_bucket_kernel<<<SCAT_BLKS, 256, 0, stream>>>(ei, et, cnt, bucket);
  prep_mfma_kernel<<<L_LAYERS, 256, 0, stream>>>(
      rel_emb, rmw0, rmb0, rmw1, rmb1, rmw2, rmb2, rmw3, rmb3, gbb);
  conv_xw_kernel<<<CONV_BLKS + XW_BLKS, 256, 0, stream>>>(
      Ww, mw0, mw1, Wwb, mw0b, mw1b, embed, Wb, xwb);

  const int gA = N_NODES / 4;         // 25000 (wave per node)

  // ---- layer 0 (mlp fuses next-layer xw as phase D)
  agg_kernel<<<gA, 256, 0, stream>>>(bucket, cnt, embed, xwb, gbb, eps, obuf);
  mlp_kernel<<<GMLP, 512, 0, stream>>>(obuf, mw0b, mb0, mw1b, mb1, W1,
                                       Wwb + D_DIM * D_DIM, Wb + D_DIM, xwb);

  // ---- layer 1
  agg_kernel<<<gA, 256, 0, stream>>>(bucket, cnt, W1, xwb,
                                     gbb + R_REL * 256, eps + 1, obuf);
  mlp_kernel<<<GMLP, 512, 0, stream>>>(obuf, mw0b + 2 * D_DIM * D_DIM, mb0 + 2 * D_DIM,
                                       mw1b + 2 * D_DIM * D_DIM, mb1 + D_DIM, out,
                                       nullptr, nullptr, nullptr);
}

// Round 11
// 365.106 us; speedup vs baseline: 1.3565x; 1.1282x over previous
//
#include <hip/hip_runtime.h>
#include <hip/hip_fp16.h>
#include <stdint.h>

#define N_NODES 100000
#define N_EDGES 640000
#define R_REL   64
#define D_DIM   128
#define L_LAYERS 2

#define CAP 32            // bucket capacity per node (P(deg>=32)~4e-13; verified no drops R8-R10)

#define LDA 136   // bf16 tile stride (128 + 8 pad)
#define LDT 264   // bf16 t-tile stride (256 + 8 pad)
#define LDFY 132  // f32 y-tile stride (128 + 4 pad)
#define LDP 264   // f16 prep activation stride (256 + 8 pad)
#define MROWS 128 // mlp tile rows
#define GMLP ((N_NODES + MROWS - 1) / MROWS)   // 782

#define SCAT_BLKS  (N_EDGES / 256)   // 2500
#define PREP_BLKS  2                 // prep role (one per layer l)
#define CONV_BLKS  128               // weight convert role (512 thr each)
#define PCX_BLKS   (PREP_BLKS + CONV_BLKS + GMLP)   // 912

typedef __attribute__((ext_vector_type(8))) short    short8;   // 8 bf16 MFMA frag
typedef __attribute__((ext_vector_type(8))) _Float16 half8;    // 8 f16 MFMA frag
typedef __attribute__((ext_vector_type(4))) unsigned short ushort4v;
typedef __attribute__((ext_vector_type(4))) float    f32x4;

__device__ __forceinline__ unsigned short f32_to_bf16(float f) {
  union { float f; uint32_t u; } v; v.f = f;
  uint32_t u = v.u;
  u += 0x7fffu + ((u >> 16) & 1u);   // RNE (finite inputs only)
  return (unsigned short)(u >> 16);
}
__device__ __forceinline__ unsigned short f2h(float f) {
  __half h = __float2half(f);
  return __half_as_ushort(h);
}
__device__ __forceinline__ __half2 u2h(unsigned int u) {
  union { unsigned int u; __half2 h; } v; v.u = u; return v.h;
}
__device__ __forceinline__ short8 frag_from_f32(const float* p) {
  float4 a = *(const float4*)p;
  float4 b = *(const float4*)(p + 4);
  short8 r;
  r[0] = (short)f32_to_bf16(a.x); r[1] = (short)f32_to_bf16(a.y);
  r[2] = (short)f32_to_bf16(a.z); r[3] = (short)f32_to_bf16(a.w);
  r[4] = (short)f32_to_bf16(b.x); r[5] = (short)f32_to_bf16(b.y);
  r[6] = (short)f32_to_bf16(b.z); r[7] = (short)f32_to_bf16(b.w);
  return r;
}
__device__ __forceinline__ half8 hfrag_from_f32(const float* p) {
  float4 a = *(const float4*)p;
  float4 b = *(const float4*)(p + 4);
  half8 r;
  r[0] = (_Float16)a.x; r[1] = (_Float16)a.y;
  r[2] = (_Float16)a.z; r[3] = (_Float16)a.w;
  r[4] = (_Float16)b.x; r[5] = (_Float16)b.y;
  r[6] = (_Float16)b.z; r[7] = (_Float16)b.w;
  return r;
}

// ---------------------------------------------------------------------------
// bucket scatter — standalone dispatch (R8 lesson: random-atomic pass must not
// be co-scheduled with streaming roles). slot = atomicAdd(cnt[dst]);
// bucket[dst*32+slot] = src | (type<<17).
// ---------------------------------------------------------------------------
__global__ __launch_bounds__(256)
void scatter_bucket_kernel(const int* __restrict__ ei, const int* __restrict__ et,
                           int* __restrict__ cnt, unsigned int* __restrict__ bucket) {
  int idx = blockIdx.x * 256 + threadIdx.x;
  int dst = ei[N_EDGES + idx];
  int slot = atomicAdd(&cnt[dst], 1);
  if (slot < CAP)
    bucket[(size_t)dst * CAP + slot] =
        (unsigned int)ei[idx] | ((unsigned int)et[idx] << 17);
}

// ---------------------------------------------------------------------------
// prep GEMM phase, 8-wave tiling (R10 fix: 4-wave version had 32 serial 2KB
// weight loads/wave -> 59us at 0.08% occupancy; 8 waves x 32 cols halves the
// serial load depth). f16 MFMA, f32 acc; final phase writes packed gbb.
// ---------------------------------------------------------------------------
template<int K, bool RELU, bool FINAL>
__device__ __forceinline__ void prep_gemm(const unsigned short* __restrict__ inb,
                                          const float* __restrict__ W,
                                          const float* __restrict__ bias,
                                          unsigned short* __restrict__ outb,
                                          unsigned short* __restrict__ gbb_l,
                                          int wave, int lrow, int quad) {
  const int n0 = wave * 32;
  f32x4 acc[4][2] = {};
  for (int ks = 0; ks < K; ks += 32) {
    half8 bf[2];
    #pragma unroll
    for (int nt = 0; nt < 2; ++nt)
      bf[nt] = hfrag_from_f32(&W[(size_t)(n0 + nt * 16 + lrow) * K + ks + quad * 8]);
    #pragma unroll
    for (int mt = 0; mt < 4; ++mt) {
      half8 a = *(const half8*)&inb[(mt * 16 + lrow) * LDP + ks + quad * 8];
      #pragma unroll
      for (int nt = 0; nt < 2; ++nt)
        acc[mt][nt] = __builtin_amdgcn_mfma_f32_16x16x32_f16(a, bf[nt], acc[mt][nt], 0, 0, 0);
    }
  }
  #pragma unroll
  for (int mt = 0; mt < 4; ++mt)
    #pragma unroll
    for (int nt = 0; nt < 2; ++nt) {
      int col = n0 + nt * 16 + lrow;
      float bb = bias[col];
      #pragma unroll
      for (int rr = 0; rr < 4; ++rr) {
        int row = mt * 16 + quad * 4 + rr;
        float v = acc[mt][nt][rr] + bb;
        if (RELU) v = fmaxf(v, 0.f);
        if (!FINAL) {
          outb[row * LDP + col] = f2h(v);
        } else {
          int slot = (col < D_DIM) ? ((col >> 1) * 4 + (col & 1))
                                   : (((col - D_DIM) >> 1) * 4 + 2 + ((col - D_DIM) & 1));
          gbb_l[row * 256 + slot] = f2h(v);
        }
      }
    }
}

// ---------------------------------------------------------------------------
// prep_conv_xw: one atomic-free fused dispatch (R9: role-fusion safe without
// atomics; R10: prep serialized after conv_xw wasted ~60us — now overlapped).
//  [0, 2)         prep role: 4-layer GEMM chain -> packed gbb (8 waves)
//  [2, 130)       weight f32->bf16 conversion (512 thr/block)
//  [130, 912)     xw(L0): 128-row tiles, mlp-phase-D shape (8 MFMA/weight-load),
//                 LDS-staged full-row output writes.
// ---------------------------------------------------------------------------
__global__ __launch_bounds__(512, 4)
void prep_conv_xw_kernel(const float* __restrict__ rel_emb,
                         const float* __restrict__ rmw0, const float* __restrict__ rmb0,
                         const float* __restrict__ rmw1, const float* __restrict__ rmb1,
                         const float* __restrict__ rmw2, const float* __restrict__ rmb2,
                         const float* __restrict__ rmw3, const float* __restrict__ rmb3,
                         unsigned short* __restrict__ gbb,
                         const float* __restrict__ Ww, const float* __restrict__ mw0,
                         const float* __restrict__ mw1,
                         unsigned short* __restrict__ Wwb, unsigned short* __restrict__ mw0b,
                         unsigned short* __restrict__ mw1b,
                         const float* __restrict__ x, const float* __restrict__ Wb,
                         unsigned short* __restrict__ xwb) {
  __shared__ unsigned short u_lds[2 * 64 * LDP];   // 67584 B (prep 2 bufs / xw tile)
  const int b = blockIdx.x;
  const int tid = threadIdx.x;     // 0..511
  const int wave = tid >> 6, lane = tid & 63;
  const int lrow = lane & 15, quad = lane >> 4;

  if (b < PREP_BLKS) {                         // ---- prep role (l = b)
    unsigned short* bufX = u_lds;              // [64][LDP]
    unsigned short* bufY = u_lds + 64 * LDP;
    const int l = b;
    for (int i = tid; i < 64 * 32; i += 512) {
      int row = i >> 5, c4 = i & 31;
      float4 v = *(const float4*)&rel_emb[(size_t)(l * R_REL + row) * D_DIM + c4 * 4];
      ushort4v s;
      s[0] = f2h(v.x); s[1] = f2h(v.y); s[2] = f2h(v.z); s[3] = f2h(v.w);
      *(ushort4v*)&bufX[row * LDP + c4 * 4] = s;
    }
    __syncthreads();
    prep_gemm<128, true, false>(bufX, rmw0 + (size_t)l * 256 * 128, rmb0 + l * 256,
                                bufY, nullptr, wave, lrow, quad);
    __syncthreads();
    prep_gemm<256, true, false>(bufY, rmw1 + (size_t)l * 256 * 256, rmb1 + l * 256,
                                bufX, nullptr, wave, lrow, quad);
    __syncthreads();
    prep_gemm<256, true, false>(bufX, rmw2 + (size_t)l * 256 * 256, rmb2 + l * 256,
                                bufY, nullptr, wave, lrow, quad);
    __syncthreads();
    prep_gemm<256, false, true>(bufY, rmw3 + (size_t)l * 256 * 256, rmb3 + l * 256,
                                nullptr, gbb + (size_t)l * R_REL * 256, wave, lrow, quad);
    return;
  }

  if (b < PREP_BLKS + CONV_BLKS) {             // ---- weight convert role
    int i = (b - PREP_BLKS) * 512 + tid;       // 0..65535
    if (i < L_LAYERS * D_DIM * D_DIM)     Wwb[i]  = f32_to_bf16(Ww[i]);
    if (i < L_LAYERS * 2 * D_DIM * D_DIM) mw0b[i] = f32_to_bf16(mw0[i]);
    if (i < L_LAYERS * 2 * D_DIM * D_DIM) mw1b[i] = f32_to_bf16(mw1[i]);
    return;
  }

  // ---- xw(L0) role: 128-row tile, phase-D shape
  unsigned short* a_lds = u_lds;               // [128][LDA] bf16 x tile; later f16 xw tile
  const int m0 = (b - PREP_BLKS - CONV_BLKS) * MROWS;

  for (int i = tid; i < MROWS * 32; i += 512) {
    int row = i >> 5, c4 = i & 31;
    int rg = m0 + row; if (rg >= N_NODES) rg = N_NODES - 1;
    float4 v = *(const float4*)&x[(size_t)rg * D_DIM + c4 * 4];
    ushort4v s;
    s[0] = f32_to_bf16(v.x); s[1] = f32_to_bf16(v.y);
    s[2] = f32_to_bf16(v.z); s[3] = f32_to_bf16(v.w);
    *(ushort4v*)&a_lds[row * LDA + c4 * 4] = s;
  }
  __syncthreads();

  const int n0 = wave * 16;
  f32x4 acc[8] = {};
  #pragma unroll
  for (int ks = 0; ks < 128; ks += 32) {
    short8 bf = frag_from_f32(&Ww[(size_t)(n0 + lrow) * D_DIM + ks + quad * 8]);
    #pragma unroll
    for (int mt = 0; mt < 8; ++mt) {
      short8 a = *(const short8*)&a_lds[(mt * 16 + lrow) * LDA + ks + quad * 8];
      acc[mt] = __builtin_amdgcn_mfma_f32_16x16x32_bf16(a, bf, acc[mt], 0, 0, 0);
    }
  }
  __syncthreads();   // a tile dead -> overlay xw f16 tile
  float bb = Wb[n0 + lrow];
  #pragma unroll
  for (int mt = 0; mt < 8; ++mt)
    #pragma unroll
    for (int rr = 0; rr < 4; ++rr) {
      int row = mt * 16 + quad * 4 + rr;
      a_lds[row * LDA + n0 + lrow] = f2h(acc[mt][rr] + bb);
    }
  __syncthreads();
  // cooperative full-row writes (short8): no partial-line amplification
  for (int i = tid; i < MROWS * 16; i += 512) {
    int row = i >> 4, seg = i & 15;
    int rg = m0 + row;
    if (rg < N_NODES)
      *(short8*)&xwb[(size_t)rg * D_DIM + seg * 8] = *(const short8*)&a_lds[row * LDA + seg * 8];
  }
}

// ---------------------------------------------------------------------------
// agg: one WAVE per node. Lane l owns cols {2l, 2l+1}; wave walks the node's
// bucket (contiguous 128B row, scalar loads); m = gamma*xw[src]+beta via one
// __hfma2, f32 register accumulation. 4-edge unroll pipelines gather latency.
// ---------------------------------------------------------------------------
__global__ __launch_bounds__(256)
void agg_kernel(const unsigned int* __restrict__ bucket, const int* __restrict__ cnt,
                const float* __restrict__ x, const unsigned short* __restrict__ xwb,
                const unsigned short* __restrict__ gbt, const float* __restrict__ eps,
                unsigned short* __restrict__ o) {
  const int lane = threadIdx.x & 63;
  const int n = __builtin_amdgcn_readfirstlane(blockIdx.x * 4 + (threadIdx.x >> 6));
  int cn = cnt[n]; if (cn > CAP) cn = CAP;
  const unsigned int* bk = bucket + (size_t)n * CAP;

  float acc0 = 0.0f, acc1 = 0.0f;
  int e = 0;
  for (; e + 4 <= cn; e += 4) {
    unsigned int d0 = bk[e], d1 = bk[e + 1], d2 = bk[e + 2], d3 = bk[e + 3];
    __half2 x0 = *(const __half2*)&xwb[(size_t)(d0 & 0x1FFFF) * D_DIM + lane * 2];
    __half2 x1 = *(const __half2*)&xwb[(size_t)(d1 & 0x1FFFF) * D_DIM + lane * 2];
    __half2 x2 = *(const __half2*)&xwb[(size_t)(d2 & 0x1FFFF) * D_DIM + lane * 2];
    __half2 x3 = *(const __half2*)&xwb[(size_t)(d3 & 0x1FFFF) * D_DIM + lane * 2];
    uint2 g0 = *(const uint2*)&gbt[(d0 >> 17) * 256 + lane * 4];
    uint2 g1 = *(const uint2*)&gbt[(d1 >> 17) * 256 + lane * 4];
    uint2 g2 = *(const uint2*)&gbt[(d2 >> 17) * 256 + lane * 4];
    uint2 g3 = *(const uint2*)&gbt[(d3 >> 17) * 256 + lane * 4];
    __half2 m0 = __hfma2(u2h(g0.x), x0, u2h(g0.y));
    __half2 m1 = __hfma2(u2h(g1.x), x1, u2h(g1.y));
    __half2 m2 = __hfma2(u2h(g2.x), x2, u2h(g2.y));
    __half2 m3 = __hfma2(u2h(g3.x), x3, u2h(g3.y));
    float2 f0 = __half22float2(m0), f1 = __half22float2(m1);
    float2 f2 = __half22float2(m2), f3 = __half22float2(m3);
    acc0 += (f0.x + f1.x) + (f2.x + f3.x);
    acc1 += (f0.y + f1.y) + (f2.y + f3.y);
  }
  if (e + 2 <= cn) {
    unsigned int d0 = bk[e], d1 = bk[e + 1];
    __half2 x0 = *(const __half2*)&xwb[(size_t)(d0 & 0x1FFFF) * D_DIM + lane * 2];
    __half2 x1 = *(const __half2*)&xwb[(size_t)(d1 & 0x1FFFF) * D_DIM + lane * 2];
    uint2 g0 = *(const uint2*)&gbt[(d0 >> 17) * 256 + lane * 4];
    uint2 g1 = *(const uint2*)&gbt[(d1 >> 17) * 256 + lane * 4];
    __half2 m0 = __hfma2(u2h(g0.x), x0, u2h(g0.y));
    __half2 m1 = __hfma2(u2h(g1.x), x1, u2h(g1.y));
    float2 f0 = __half22float2(m0), f1 = __half22float2(m1);
    acc0 += f0.x + f1.x;
    acc1 += f0.y + f1.y;
    e += 2;
  }
  if (e < cn) {
    unsigned int d0 = bk[e];
    __half2 x0 = *(const __half2*)&xwb[(size_t)(d0 & 0x1FFFF) * D_DIM + lane * 2];
    uint2 g0 = *(const uint2*)&gbt[(d0 >> 17) * 256 + lane * 4];
    __half2 m0 = __hfma2(u2h(g0.x), x0, u2h(g0.y));
    float2 f0 = __half22float2(m0);
    acc0 += f0.x;
    acc1 += f0.y;
  }

  const float e1v = 1.0f + eps[0];
  float2 xr = *(const float2*)&x[(size_t)n * D_DIM + lane * 2];
  unsigned int w = (unsigned int)f32_to_bf16(e1v * xr.x + acc0)
                 | ((unsigned int)f32_to_bf16(e1v * xr.y + acc1) << 16);
  *(unsigned int*)&o[(size_t)n * D_DIM + lane * 2] = w;
}

// ---------------------------------------------------------------------------
// mlp: block = 128 nodes, 8 waves. All outputs staged through LDS and written
// as full cache lines (float4 / short8 rows) — no partial-line amplification.
// LDS overlay timeline in one 67584 B buffer:
//   o tile [128][136]bf16 -> t tile [128][264]bf16 -> y tile [128][132]f32
//   -> (D) xw tile [128][136]f16
// ---------------------------------------------------------------------------
__global__ __launch_bounds__(512, 4)
void mlp_kernel(const unsigned short* __restrict__ o,
                const unsigned short* __restrict__ w0b, const float* __restrict__ b0,
                const unsigned short* __restrict__ w1b, const float* __restrict__ b1,
                float* __restrict__ y,
                const unsigned short* __restrict__ WwNb,  // next-layer Ww bf16 (or null)
                const float* __restrict__ WbN,            // next-layer bias
                unsigned short* __restrict__ xwbN) {      // next-layer xw f16 out
  __shared__ unsigned short u_lds[MROWS * LDT];   // 67584 B
  unsigned short* a_lds = u_lds;          // [128][LDA] bf16 o tile
  unsigned short* t_lds = u_lds;          // [128][LDT] bf16 t tile
  float*          yf    = (float*)u_lds;  // [128][LDFY] f32 y tile
  unsigned short* xs    = u_lds;          // [128][LDA] f16 xw tile

  const int tid = threadIdx.x;     // 0..511
  const int m0 = blockIdx.x * MROWS;

  // ---- stage o tile (clamp tail rows)
  for (int i = tid; i < MROWS * 16; i += 512) {
    int row = i >> 4, seg = i & 15;
    int rg = m0 + row; if (rg >= N_NODES) rg = N_NODES - 1;
    *(short8*)&a_lds[row * LDA + seg * 8] =
        *(const short8*)&o[(size_t)rg * D_DIM + seg * 8];
  }
  __syncthreads();

  const int wave = tid >> 6, lane = tid & 63;
  const int lrow = lane & 15, quad = lane >> 4;

  // ---- B: t = relu(o @ w0^T + b0); wave covers t cols [wave*32, +32)
  {
    const int n0 = wave * 32;
    f32x4 acc[8][2] = {};
    #pragma unroll
    for (int ks = 0; ks < 128; ks += 32) {
      short8 bf0 = *(const short8*)&w0b[(n0 + lrow) * D_DIM + ks + quad * 8];
      short8 bf1 = *(const short8*)&w0b[(n0 + 16 + lrow) * D_DIM + ks + quad * 8];
      #pragma unroll
      for (int mt = 0; mt < 8; ++mt) {
        short8 a = *(const short8*)&a_lds[(mt * 16 + lrow) * LDA + ks + quad * 8];
        acc[mt][0] = __builtin_amdgcn_mfma_f32_16x16x32_bf16(a, bf0, acc[mt][0], 0, 0, 0);
        acc[mt][1] = __builtin_amdgcn_mfma_f32_16x16x32_bf16(a, bf1, acc[mt][1], 0, 0, 0);
      }
    }
    __syncthreads();   // a dead
    float bb0 = b0[n0 + lrow], bb1 = b0[n0 + 16 + lrow];
    #pragma unroll
    for (int mt = 0; mt < 8; ++mt)
      #pragma unroll
      for (int rr = 0; rr < 4; ++rr) {
        int row = mt * 16 + quad * 4 + rr;
        t_lds[row * LDT + n0 + lrow]      = f32_to_bf16(fmaxf(acc[mt][0][rr] + bb0, 0.0f));
        t_lds[row * LDT + n0 + 16 + lrow] = f32_to_bf16(fmaxf(acc[mt][1][rr] + bb1, 0.0f));
      }
  }
  __syncthreads();

  // ---- C: y = t @ w1^T + b1; wave covers y cols [wave*16, +16)
  {
    const int n0 = wave * 16;
    f32x4 acc[8] = {};
    #pragma unroll
    for (int ks = 0; ks < 256; ks += 32) {
      short8 bf = *(const short8*)&w1b[(n0 + lrow) * 2 * D_DIM + ks + quad * 8];
      #pragma unroll
      for (int mt = 0; mt < 8; ++mt) {
        short8 a = *(const short8*)&t_lds[(mt * 16 + lrow) * LDT + ks + quad * 8];
        acc[mt] = __builtin_amdgcn_mfma_f32_16x16x32_bf16(a, bf, acc[mt], 0, 0, 0);
      }
    }
    __syncthreads();   // t dead
    float bb = b1[n0 + lrow];
    #pragma unroll
    for (int mt = 0; mt < 8; ++mt)
      #pragma unroll
      for (int rr = 0; rr < 4; ++rr) {
        int row = mt * 16 + quad * 4 + rr;
        yf[row * LDFY + n0 + lrow] = acc[mt][rr] + bb;
      }
  }
  __syncthreads();   // y tile complete

  // ---- cooperative y write: full 512B rows, float4 per lane
  for (int i = tid; i < MROWS * 32; i += 512) {
    int row = i >> 5, c4 = i & 31;
    int rg = m0 + row;
    if (rg < N_NODES)
      *(float4*)&y[(size_t)rg * D_DIM + c4 * 4] = *(const float4*)&yf[row * LDFY + c4 * 4];
  }

  // ---- D (fused next-layer xw): xwbN = f16(y @ WwN^T + WbN)
  if (xwbN) {
    const int n0 = wave * 16;
    f32x4 acc[8] = {};
    #pragma unroll
    for (int ks = 0; ks < 128; ks += 32) {
      short8 bf = *(const short8*)&WwNb[(n0 + lrow) * D_DIM + ks + quad * 8];
      #pragma unroll
      for (int mt = 0; mt < 8; ++mt) {
        short8 a = frag_from_f32(&yf[(mt * 16 + lrow) * LDFY + ks + quad * 8]);
        acc[mt] = __builtin_amdgcn_mfma_f32_16x16x32_bf16(a, bf, acc[mt], 0, 0, 0);
      }
    }
    __syncthreads();   // yf dead (also guarantees y-write loop reads done)
    float bb = WbN[n0 + lrow];
    #pragma unroll
    for (int mt = 0; mt < 8; ++mt)
      #pragma unroll
      for (int rr = 0; rr < 4; ++rr) {
        int row = mt * 16 + quad * 4 + rr;
        xs[row * LDA + n0 + lrow] = f2h(acc[mt][rr] + bb);
      }
    __syncthreads();   // xw tile complete
    // cooperative xwb write: full 256B rows, short8 per lane
    for (int i = tid; i < MROWS * 16; i += 512) {
      int row = i >> 4, seg = i & 15;
      int rg = m0 + row;
      if (rg < N_NODES)
        *(short8*)&xwbN[(size_t)rg * D_DIM + seg * 8] = *(const short8*)&xs[row * LDA + seg * 8];
    }
  }
}

// ---------------------------------------------------------------------------
extern "C" void kernel_launch(void* const* d_in, const int* in_sizes, int n_in,
                              void* d_out, int out_size, void* d_ws, size_t ws_size,
                              hipStream_t stream) {
  const int*   ei      = (const int*)d_in[0];
  const int*   et      = (const int*)d_in[1];
  const float* embed   = (const float*)d_in[2];
  const float* rel_emb = (const float*)d_in[3];
  const float* rmw0 = (const float*)d_in[4];  const float* rmb0 = (const float*)d_in[5];
  const float* rmw1 = (const float*)d_in[6];  const float* rmb1 = (const float*)d_in[7];
  const float* rmw2 = (const float*)d_in[8];  const float* rmb2 = (const float*)d_in[9];
  const float* rmw3 = (const float*)d_in[10]; const float* rmb3 = (const float*)d_in[11];
  const float* Ww   = (const float*)d_in[12]; const float* Wb   = (const float*)d_in[13];
  const float* mw0  = (const float*)d_in[14]; const float* mb0  = (const float*)d_in[15];
  const float* mw1  = (const float*)d_in[16]; const float* mb1  = (const float*)d_in[17];
  const float* eps  = (const float*)d_in[18];
  float* out = (float*)d_out;

  // workspace layout
  float*          W1   = (float*)d_ws;                          // N*D f32
  unsigned short* xwb  = (unsigned short*)(W1 + (size_t)N_NODES * D_DIM);  // N*D f16
  unsigned short* gbb  = xwb + (size_t)N_NODES * D_DIM;         // L*R*256 f16
  unsigned short* Wwb  = gbb + L_LAYERS * R_REL * 256;          // L*128*128 bf16
  unsigned short* mw0b = Wwb + L_LAYERS * D_DIM * D_DIM;        // L*256*128 bf16
  unsigned short* mw1b = mw0b + L_LAYERS * 2 * D_DIM * D_DIM;   // L*128*256 bf16
  int*   cnt     = (int*)(mw1b + L_LAYERS * 2 * D_DIM * D_DIM); // N
  unsigned int* bucket = (unsigned int*)(cnt + N_NODES);        // N*CAP u32
  unsigned short* obuf = (unsigned short*)(bucket + (size_t)N_NODES * CAP); // N*D bf16

  // ---- preprocessing: atomic pass alone; then one atomic-free fused pass
  hipMemsetAsync(cnt, 0, N_NODES * sizeof(int), stream);
  scatter_bucket_kernel<<<SCAT_BLKS, 256, 0, stream>>>(ei, et, cnt, bucket);
  prep_conv_xw_kernel<<<PCX_BLKS, 512, 0, stream>>>(
      rel_emb, rmw0, rmb0, rmw1, rmb1, rmw2, rmb2, rmw3, rmb3, gbb,
      Ww, mw0, mw1, Wwb, mw0b, mw1b, embed, Wb, xwb);

  const int gA = N_NODES / 4;         // 25000 (wave per node)

  // ---- layer 0 (mlp fuses next-layer xw as phase D)
  agg_kernel<<<gA, 256, 0, stream>>>(bucket, cnt, embed, xwb, gbb, eps, obuf);
  mlp_kernel<<<GMLP, 512, 0, stream>>>(obuf, mw0b, mb0, mw1b, mb1, W1,
                                       Wwb + D_DIM * D_DIM, Wb + D_DIM, xwb);

  // ---- layer 1
  agg_kernel<<<gA, 256, 0, stream>>>(bucket, cnt, W1, xwb,
                                     gbb + R_REL * 256, eps + 1, obuf);
  mlp_kernel<<<GMLP, 512, 0, stream>>>(obuf, mw0b + 2 * D_DIM * D_DIM, mb0 + 2 * D_DIM,
                                       mw1b + 2 * D_DIM * D_DIM, mb1 + D_DIM, out,
                                       nullptr, nullptr, nullptr);
}